// Round 11
// baseline (208.011 us; speedup 1.0000x reference)
//
#include <hip/hip_runtime.h>
#include <stdint.h>
#include <math.h>

// Problem constants (from reference)
#define NB 16
#define NK 16384
#define NADD 32
#define NP 36            // 2^RANK + ADD = 4 + 32
#define DIM 65536        // IN_DIM == OUT_DIM

// geometry: 512 blocks x 512 threads, 32 KB LDS, 2 blocks/CU co-resident
#define TPB 512
#define NCH2 8           // output chunks per batch row
#define CHW2 8192        // chunk width (floats) -> 32 KB LDS accumulator

typedef float f32x4 __attribute__((ext_vector_type(4)));

__device__ __forceinline__ uint32_t rotl32(uint32_t x, uint32_t r) {
    return (x << r) | (x >> (32u - r));
}

// Threefry-2x32 (20 rounds), key = (0, 42); partitionable mode: ctr=(0,idx),
// bits = out0 ^ out1. CONFIRMED bit-correct (rounds 1-10).
__device__ __forceinline__ uint32_t tf_bits(uint32_t idx) {
    const uint32_t K1 = 42u;
    const uint32_t K2 = 0x1BD11BDAu ^ 42u;
    uint32_t x0 = 0u;
    uint32_t x1 = idx + K1;
#define TF_ROUND(r) { x0 += x1; x1 = rotl32(x1, r); x1 ^= x0; }
#define TF_G(a,b,c,d) TF_ROUND(a) TF_ROUND(b) TF_ROUND(c) TF_ROUND(d)
    TF_G(13,15,26,6)   x0 += K1;  x1 += K2 + 1u;
    TF_G(17,29,16,24)  x0 += K2;  x1 += 2u;
    TF_G(13,15,26,6)              x1 += K1 + 3u;
    TF_G(17,29,16,24)  x0 += K1;  x1 += K2 + 4u;
    TF_G(13,15,26,6)   x0 += K2;  x1 += 5u;
#undef TF_G
#undef TF_ROUND
    return x0 ^ x1;
}

// Bit-exact XLA:CPU f32 exp (Cephes/Eigen pexp), strict per-op f32 rounding,
// no FMA contraction. CONFIRMED: rounds 3-10 passed with absmax 7.8e-3.
__device__ __forceinline__ float xla_expf(float x0) {
    float x = fminf(fmaxf(x0, -88.3762626647949f), 88.3762626647950f);
    const float fx = floorf(__fadd_rn(__fmul_rn(x, 1.44269504088896341f), 0.5f));
    const float tmp = __fmul_rn(fx, 0.693359375f);
    float z = __fmul_rn(fx, -2.12194440e-4f);
    float r = __fsub_rn(x, tmp);
    r = __fsub_rn(r, z);
    z = __fmul_rn(r, r);
    float y = 1.9875691500E-4f;
    y = __fadd_rn(__fmul_rn(y, r), 1.3981999507E-3f);
    y = __fadd_rn(__fmul_rn(y, r), 8.3334519073E-3f);
    y = __fadd_rn(__fmul_rn(y, r), 4.1665795894E-2f);
    y = __fadd_rn(__fmul_rn(y, r), 1.6666665459E-1f);
    y = __fadd_rn(__fmul_rn(y, r), 5.0000001201E-1f);
    y = __fadd_rn(__fmul_rn(y, z), r);
    y = __fadd_rn(y, 1.0f);
    const int n = (int)fx;
    const float p2n = __uint_as_float((uint32_t)(n + 127) << 23);
    return fmaxf(__fmul_rn(y, p2n), x0);
}

// Shared generation: fills packed[36] ((out<<16)|in) and w[36] (normalized
// weight scale*prop). Identical arithmetic to all passing rounds (3-10).
__device__ __forceinline__ void gen_point(const float4 r, uint32_t tid,
                                          uint32_t* packed, float* w) {
    const float e0 = xla_expf(-r.x);
    const float e1 = xla_expf(-r.y);
    const float s0 = __fdiv_rn(1.0f, __fadd_rn(1.0f, e0));
    const float s1 = __fdiv_rn(1.0f, __fadd_rn(1.0f, e1));
    const float m0 = __fmul_rn(s0, 65535.0f);
    const float m1 = __fmul_rn(s1, 65535.0f);

    const float a2 = r.z + 2.0f;
    const float sp = fmaxf(a2, 0.0f) + log1pf(expf(-fabsf(a2)));
    const float sigma = (sp + 1e-6f) * 65536.0f;
    const float val = r.w;

    const float f0 = floorf(m0), c0 = ceilf(m0);
    const float f1 = floorf(m1), c1 = ceilf(m1);
    {
        const float cd0[4] = {f0, f0, c0, c0};
        const float cd1[4] = {f1, c1, f1, c1};
        #pragma unroll
        for (int p = 0; p < 4; ++p) {
            const float z0 = (cd0[p] - m0) / sigma;
            const float z1 = (cd1[p] - m1) / sigma;
            w[p] = expf(-0.5f * (z0*z0 + z1*z1));
            packed[p] = ((uint32_t)(int)cd0[p] << 16) | (uint32_t)(int)cd1[p];
        }
    }
    const float ONE_MEPS = (float)(1.0 - 1e-6);
    const uint32_t base = tid * 64u;
    #pragma unroll
    for (int a = 0; a < NADD; ++a) {
        const uint32_t bb0 = tf_bits(base + 2u*(uint32_t)a);
        const uint32_t bb1 = tf_bits(base + 2u*(uint32_t)a + 1u);
        const float u0 = __fmul_rn(__uint_as_float((bb0 >> 9) | 0x3f800000u) - 1.0f, ONE_MEPS);
        const float u1 = __fmul_rn(__uint_as_float((bb1 >> 9) | 0x3f800000u) - 1.0f, ONE_MEPS);
        const float s0f = floorf(__fmul_rn(u0, 65536.0f));
        const float s1f = floorf(__fmul_rn(u1, 65536.0f));
        const float z0 = (s0f - m0) / sigma;
        const float z1 = (s1f - m1) / sigma;
        w[4 + a] = expf(-0.5f * (z0*z0 + z1*z1));
        packed[4 + a] = ((uint32_t)(int)s0f << 16) | (uint32_t)(int)s1f;
    }
    float denom = 0.0f;
    #pragma unroll
    for (int p = 0; p < NP; ++p) denom += w[p] + 1e-6f;
    const float scale = val / denom;
    #pragma unroll
    for (int p = 0; p < NP; ++p) w[p] *= scale;
}

// y[b, o] = bias[o] broadcast (y is re-poisoned 0xAA before every call).
__global__ __launch_bounds__(256) void init_bias_kernel(
    const float4* __restrict__ bias4, float4* __restrict__ y4)
{
    const int i = blockIdx.x * 256 + threadIdx.x;   // [0, NB*DIM/4)
    y4[i] = bias4[i & 16383];
}

// F1: gen + LDS chunk accumulate + COALESCED global-atomic epilogue into y.
// Deletes the 128 MB partials write + 128 MB f2 re-read of round 10.
// Atomics here are dense: 64 consecutive lanes per instruction (vs round-3's
// scattered 4B atomics at 31 B/granule). ~72% of chunk positions are zero ->
// v!=0 predication skips them (memory-side atomics update per dword).
__global__ __launch_bounds__(TPB, 4) void f1_gen_atomic(
    const float*  __restrict__ x,     // (NB, DIM)
    const float4* __restrict__ res4,  // (NB, NK, 4)
    float* __restrict__ y)            // (NB, DIM), pre-filled with bias
{
    __shared__ float acc[CHW2];       // 32 KB -> 2 blocks/CU
    f32x4* const acc4 = reinterpret_cast<f32x4*>(acc);
    const int blk = blockIdx.x;
    const uint32_t tid = (uint32_t)blk * TPB + threadIdx.x;  // global point id
    const int b = (int)(tid >> 14);

    uint32_t packed[NP];
    float    w[NP];
    gen_point(res4[tid], tid, packed, w);

    const float* __restrict__ xrow = x + ((size_t)b << 16);
    #pragma unroll
    for (int p = 0; p < NP; ++p) {
        w[p] *= xrow[packed[p] & 0xFFFFu];
        packed[p] = packed[p] >> 16;            // out in [0, 65536)
    }

    float* __restrict__ yrow = y + ((size_t)b << 16);
    #pragma unroll 1
    for (uint32_t c = 0; c < NCH2; ++c) {
        // zero: 2048 f32x4 / 512 threads = 4 iters
        #pragma unroll
        for (int j = 0; j < 4; ++j)
            acc4[j * TPB + threadIdx.x] = (f32x4)(0.0f);
        __syncthreads();
        #pragma unroll
        for (int p = 0; p < NP; ++p) {
            if ((packed[p] >> 13) == c)
                atomicAdd(&acc[packed[p] & (CHW2 - 1)], w[p]);
        }
        __syncthreads();
        // coalesced atomic drain: lane i handles positions j*512+i (dense
        // across the wave); skip zeros (adding +0.0f is a no-op on y).
        float* __restrict__ ydst = yrow + c * CHW2;
        #pragma unroll
        for (int j = 0; j < 16; ++j) {
            const int idx = j * TPB + (int)threadIdx.x;   // [0, 8192)
            const float v = acc[idx];
            if (v != 0.0f) unsafeAtomicAdd(&ydst[idx], v);
        }
        __syncthreads();   // protect acc from next pass's zeroing
    }
}

// ---------------- fallback (ws-free, round-3 passing kernel) -------------
// (kept only as reference; primary path is also ws-free and always taken)

__global__ __launch_bounds__(256) void hyper_scatter(
    const float*  __restrict__ x,
    const float4* __restrict__ res4,
    float*        __restrict__ y)
{
    const int tid = blockIdx.x * 256 + threadIdx.x;
    const int b = tid >> 14;
    uint32_t packed[NP];
    float    w[NP];
    gen_point(res4[tid], (uint32_t)tid, packed, w);
    const float* __restrict__ xrow = x + ((size_t)b << 16);
    float*       __restrict__ yrow = y + ((size_t)b << 16);
    #pragma unroll
    for (int p = 0; p < NP; ++p) {
        const float xv = xrow[packed[p] & 0xFFFFu];
        unsafeAtomicAdd(&yrow[packed[p] >> 16], w[p] * xv);
    }
}

extern "C" void kernel_launch(void* const* d_in, const int* in_sizes, int n_in,
                              void* d_out, int out_size, void* d_ws, size_t ws_size,
                              hipStream_t stream) {
    const float*  x     = (const float*)d_in[0];   // (16, 65536) f32
    const float4* res4  = (const float4*)d_in[1];  // (16, 16384, 4) f32
    const float4* bias4 = (const float4*)d_in[2];  // (65536,) f32
    float* y = (float*)d_out;                      // (16, 65536) f32

    (void)d_ws; (void)ws_size;  // no workspace needed

    init_bias_kernel<<<(NB * DIM / 4) / 256, 256, 0, stream>>>(bias4, (float4*)y);
    f1_gen_atomic<<<NB * NK / TPB, TPB, 0, stream>>>(x, res4, y);
}

// Round 12
// 163.463 us; speedup vs baseline: 1.2725x; 1.2725x over previous
//
#include <hip/hip_runtime.h>
#include <stdint.h>
#include <math.h>

// Problem constants (from reference)
#define NB 16
#define NK 16384
#define NADD 32
#define NP 36            // 2^RANK + ADD = 4 + 32
#define DIM 65536        // IN_DIM == OUT_DIM

// geometry: 512 blocks x 512 threads, 32 KB LDS, 2 blocks/CU co-resident
#define TPB 512
#define GPB2 32          // groups per batch row (NK / TPB)
#define NCH2 8           // output chunks per batch row
#define CHW2 8192        // chunk width (floats) -> 32 KB LDS accumulator

typedef float f32x4 __attribute__((ext_vector_type(4)));
typedef unsigned int u32x2 __attribute__((ext_vector_type(2)));

__device__ __forceinline__ uint32_t rotl32(uint32_t x, uint32_t r) {
    return (x << r) | (x >> (32u - r));
}

// Threefry-2x32 (20 rounds), key = (0, 42); partitionable mode: ctr=(0,idx),
// bits = out0 ^ out1. CONFIRMED bit-correct (rounds 1-11).
__device__ __forceinline__ uint32_t tf_bits(uint32_t idx) {
    const uint32_t K1 = 42u;
    const uint32_t K2 = 0x1BD11BDAu ^ 42u;
    uint32_t x0 = 0u;
    uint32_t x1 = idx + K1;
#define TF_ROUND(r) { x0 += x1; x1 = rotl32(x1, r); x1 ^= x0; }
#define TF_G(a,b,c,d) TF_ROUND(a) TF_ROUND(b) TF_ROUND(c) TF_ROUND(d)
    TF_G(13,15,26,6)   x0 += K1;  x1 += K2 + 1u;
    TF_G(17,29,16,24)  x0 += K2;  x1 += 2u;
    TF_G(13,15,26,6)              x1 += K1 + 3u;
    TF_G(17,29,16,24)  x0 += K1;  x1 += K2 + 4u;
    TF_G(13,15,26,6)   x0 += K2;  x1 += 5u;
#undef TF_G
#undef TF_ROUND
    return x0 ^ x1;
}

// Bit-exact XLA:CPU f32 exp (Cephes/Eigen pexp), strict per-op f32 rounding,
// no FMA contraction. CONFIRMED: rounds 3-11 passed with absmax 7.8e-3.
__device__ __forceinline__ float xla_expf(float x0) {
    float x = fminf(fmaxf(x0, -88.3762626647949f), 88.3762626647950f);
    const float fx = floorf(__fadd_rn(__fmul_rn(x, 1.44269504088896341f), 0.5f));
    const float tmp = __fmul_rn(fx, 0.693359375f);
    float z = __fmul_rn(fx, -2.12194440e-4f);
    float r = __fsub_rn(x, tmp);
    r = __fsub_rn(r, z);
    z = __fmul_rn(r, r);
    float y = 1.9875691500E-4f;
    y = __fadd_rn(__fmul_rn(y, r), 1.3981999507E-3f);
    y = __fadd_rn(__fmul_rn(y, r), 8.3334519073E-3f);
    y = __fadd_rn(__fmul_rn(y, r), 4.1665795894E-2f);
    y = __fadd_rn(__fmul_rn(y, r), 1.6666665459E-1f);
    y = __fadd_rn(__fmul_rn(y, r), 5.0000001201E-1f);
    y = __fadd_rn(__fmul_rn(y, z), r);
    y = __fadd_rn(y, 1.0f);
    const int n = (int)fx;
    const float p2n = __uint_as_float((uint32_t)(n + 127) << 23);
    return fmaxf(__fmul_rn(y, p2n), x0);
}

// Shared generation: fills packed[36] ((out<<16)|in) and w[36] (normalized
// weight scale*prop). Identical arithmetic to all passing rounds (3-11).
__device__ __forceinline__ void gen_point(const float4 r, uint32_t tid,
                                          uint32_t* packed, float* w) {
    const float e0 = xla_expf(-r.x);
    const float e1 = xla_expf(-r.y);
    const float s0 = __fdiv_rn(1.0f, __fadd_rn(1.0f, e0));
    const float s1 = __fdiv_rn(1.0f, __fadd_rn(1.0f, e1));
    const float m0 = __fmul_rn(s0, 65535.0f);
    const float m1 = __fmul_rn(s1, 65535.0f);

    const float a2 = r.z + 2.0f;
    const float sp = fmaxf(a2, 0.0f) + log1pf(expf(-fabsf(a2)));
    const float sigma = (sp + 1e-6f) * 65536.0f;
    const float val = r.w;

    const float f0 = floorf(m0), c0 = ceilf(m0);
    const float f1 = floorf(m1), c1 = ceilf(m1);
    {
        const float cd0[4] = {f0, f0, c0, c0};
        const float cd1[4] = {f1, c1, f1, c1};
        #pragma unroll
        for (int p = 0; p < 4; ++p) {
            const float z0 = (cd0[p] - m0) / sigma;
            const float z1 = (cd1[p] - m1) / sigma;
            w[p] = expf(-0.5f * (z0*z0 + z1*z1));
            packed[p] = ((uint32_t)(int)cd0[p] << 16) | (uint32_t)(int)cd1[p];
        }
    }
    const float ONE_MEPS = (float)(1.0 - 1e-6);
    const uint32_t base = tid * 64u;
    #pragma unroll
    for (int a = 0; a < NADD; ++a) {
        const uint32_t bb0 = tf_bits(base + 2u*(uint32_t)a);
        const uint32_t bb1 = tf_bits(base + 2u*(uint32_t)a + 1u);
        const float u0 = __fmul_rn(__uint_as_float((bb0 >> 9) | 0x3f800000u) - 1.0f, ONE_MEPS);
        const float u1 = __fmul_rn(__uint_as_float((bb1 >> 9) | 0x3f800000u) - 1.0f, ONE_MEPS);
        const float s0f = floorf(__fmul_rn(u0, 65536.0f));
        const float s1f = floorf(__fmul_rn(u1, 65536.0f));
        const float z0 = (s0f - m0) / sigma;
        const float z1 = (s1f - m1) / sigma;
        w[4 + a] = expf(-0.5f * (z0*z0 + z1*z1));
        packed[4 + a] = ((uint32_t)(int)s0f << 16) | (uint32_t)(int)s1f;
    }
    float denom = 0.0f;
    #pragma unroll
    for (int p = 0; p < NP; ++p) denom += w[p] + 1e-6f;
    const float scale = val / denom;
    #pragma unroll
    for (int p = 0; p < NP; ++p) w[p] *= scale;
}

// bf16 RNE pack of two f32 into one u32 (a -> low 16, b -> high 16)
__device__ __forceinline__ uint32_t bf16pair(float a, float b) {
    uint32_t ua = __float_as_uint(a), ub = __float_as_uint(b);
    ua = (ua + 0x7FFFu + ((ua >> 16) & 1u)) >> 16;
    ub = (ub + 0x7FFFu + ((ub >> 16) & 1u)) >> 16;
    return ua | (ub << 16);
}

// ------------- primary: 512x512, bf16 partials (64 MB), 2 blocks/CU -------
// Partial layout (CORRECT strides, round-9 bug fixed):
//   row per block: DIM bf16 = 32768 u32  -> row offset = blk << 15 (u32)
//   chunk c: CHW2=8192 bf16 = 4096 u32   -> chunk offset = c * 4096 (u32)

__global__ __launch_bounds__(TPB, 4) void f1_gen_reduce_bf16(
    const float*  __restrict__ x,     // (NB, DIM)
    const float4* __restrict__ res4,  // (NB, NK, 4)
    uint32_t* __restrict__ part)      // [NB*GPB2][DIM] bf16
{
    __shared__ float acc[CHW2];       // 32 KB -> 2 blocks/CU
    f32x4* const acc4 = reinterpret_cast<f32x4*>(acc);
    const int blk = blockIdx.x;
    const uint32_t tid = (uint32_t)blk * TPB + threadIdx.x;  // global point id
    const int b = (int)(tid >> 14);

    uint32_t packed[NP];
    float    w[NP];
    gen_point(res4[tid], tid, packed, w);

    const float* __restrict__ xrow = x + ((size_t)b << 16);
    #pragma unroll
    for (int p = 0; p < NP; ++p) {
        w[p] *= xrow[packed[p] & 0xFFFFu];
        packed[p] = packed[p] >> 16;            // out in [0, 65536)
    }

    // initial zero (once): 2048 f32x4 / 512 threads = 4 iters
    #pragma unroll
    for (int j = 0; j < 4; ++j)
        acc4[j * TPB + threadIdx.x] = (f32x4)(0.0f);
    __syncthreads();

    uint32_t* __restrict__ dst = part + ((size_t)blk << 15);  // u32 row
    #pragma unroll 1
    for (uint32_t c = 0; c < NCH2; ++c) {
        #pragma unroll
        for (int p = 0; p < NP; ++p) {
            if ((packed[p] >> 13) == c)
                atomicAdd(&acc[packed[p] & (CHW2 - 1)], w[p]);
        }
        __syncthreads();
        // merged drain: pack bf16, nontemporal store, re-zero in one sweep.
        // chunk = 4096 u32 = 2048 u32x2; 2048/512 = 4 iters
        u32x2* __restrict__ dst2 =
            reinterpret_cast<u32x2*>(dst + (size_t)c * 4096);
        #pragma unroll
        for (int j = 0; j < 4; ++j) {
            const int idx = j * TPB + (int)threadIdx.x;   // [0, 2048) u32x2
            const f32x4 v = acc4[idx];
            const u32x2 o = { bf16pair(v.x, v.y), bf16pair(v.z, v.w) };
            __builtin_nontemporal_store(o, &dst2[idx]);
            acc4[idx] = (f32x4)(0.0f);                    // re-zero for next pass
        }
        __syncthreads();
    }
}

// F2: y = bias + sum_g bf16 part rows; fully coalesced, nontemporal.
// Row = 16384 u32x2; thread handles one u32x2 (4 outputs) per row, 32 rows.
__global__ __launch_bounds__(256) void f2_final_bf16(
    const u32x2* __restrict__ part2,  // [NB*GPB2][16384] u32x2
    const f32x4* __restrict__ bias4,
    f32x4* __restrict__ y4)
{
    const int i = blockIdx.x * 256 + threadIdx.x;  // [0, NB*DIM/4)
    const int o4 = i & 16383;                      // u32x2 index within row
    const int b = i >> 14;
    f32x4 s = bias4[o4];
    #pragma unroll
    for (int g = 0; g < GPB2; ++g) {
        const u32x2 p = __builtin_nontemporal_load(
            &part2[(((size_t)(b * GPB2 + g)) << 14) + o4]);
        s.x += __uint_as_float(p.x << 16);
        s.y += __uint_as_float(p.x & 0xFFFF0000u);
        s.z += __uint_as_float(p.y << 16);
        s.w += __uint_as_float(p.y & 0xFFFF0000u);
    }
    __builtin_nontemporal_store(s, &y4[i]);
}

// ------------- secondary: round-10 proven f32 path (128 MB ws) -----------

__global__ __launch_bounds__(TPB, 4) void f1_gen_reduce_512(
    const float*  __restrict__ x,
    const float4* __restrict__ res4,
    float* __restrict__ part)         // [NB*GPB2][DIM] f32
{
    __shared__ float acc[CHW2];
    f32x4* const acc4 = reinterpret_cast<f32x4*>(acc);
    const int blk = blockIdx.x;
    const uint32_t tid = (uint32_t)blk * TPB + threadIdx.x;
    const int b = (int)(tid >> 14);

    uint32_t packed[NP];
    float    w[NP];
    gen_point(res4[tid], tid, packed, w);

    const float* __restrict__ xrow = x + ((size_t)b << 16);
    #pragma unroll
    for (int p = 0; p < NP; ++p) {
        w[p] *= xrow[packed[p] & 0xFFFFu];
        packed[p] = packed[p] >> 16;
    }

    float* __restrict__ dst = part + ((size_t)blk << 16);
    #pragma unroll 1
    for (uint32_t c = 0; c < NCH2; ++c) {
        #pragma unroll
        for (int j = 0; j < 4; ++j)
            acc4[j * TPB + threadIdx.x] = (f32x4)(0.0f);
        __syncthreads();
        #pragma unroll
        for (int p = 0; p < NP; ++p) {
            if ((packed[p] >> 13) == c)
                atomicAdd(&acc[packed[p] & (CHW2 - 1)], w[p]);
        }
        __syncthreads();
        f32x4* __restrict__ dst4 = reinterpret_cast<f32x4*>(dst + c * CHW2);
        #pragma unroll
        for (int j = 0; j < 4; ++j)
            __builtin_nontemporal_store(acc4[j * TPB + threadIdx.x],
                                        &dst4[j * TPB + threadIdx.x]);
        __syncthreads();
    }
}

__global__ __launch_bounds__(256) void f2_final_32(
    const f32x4* __restrict__ part4,
    const f32x4* __restrict__ bias4,
    f32x4* __restrict__ y4)
{
    const int i = blockIdx.x * 256 + threadIdx.x;
    const int o4 = i & 16383;
    const int b = i >> 14;
    f32x4 s = bias4[o4];
    #pragma unroll
    for (int g = 0; g < GPB2; ++g) {
        const f32x4 p = __builtin_nontemporal_load(
            &part4[(((size_t)(b * GPB2 + g)) << 14) + o4]);
        s += p;
    }
    __builtin_nontemporal_store(s, &y4[i]);
}

// ---------------- fallback path (round-3 passing kernel) ----------------

__global__ __launch_bounds__(256) void init_bias_kernel(
    const float4* __restrict__ bias4, float4* __restrict__ y4)
{
    const int i = blockIdx.x * 256 + threadIdx.x;
    y4[i] = bias4[i & 16383];
}

__global__ __launch_bounds__(256) void hyper_scatter(
    const float*  __restrict__ x,
    const float4* __restrict__ res4,
    float*        __restrict__ y)
{
    const int tid = blockIdx.x * 256 + threadIdx.x;
    const int b = tid >> 14;
    uint32_t packed[NP];
    float    w[NP];
    gen_point(res4[tid], (uint32_t)tid, packed, w);
    const float* __restrict__ xrow = x + ((size_t)b << 16);
    float*       __restrict__ yrow = y + ((size_t)b << 16);
    #pragma unroll
    for (int p = 0; p < NP; ++p) {
        const float xv = xrow[packed[p] & 0xFFFFu];
        unsafeAtomicAdd(&yrow[packed[p] >> 16], w[p] * xv);
    }
}

extern "C" void kernel_launch(void* const* d_in, const int* in_sizes, int n_in,
                              void* d_out, int out_size, void* d_ws, size_t ws_size,
                              hipStream_t stream) {
    const float*  x     = (const float*)d_in[0];   // (16, 65536) f32
    const float4* res4  = (const float4*)d_in[1];  // (16, 16384, 4) f32
    const float4* bias4 = (const float4*)d_in[2];  // (65536,) f32
    float* y = (float*)d_out;                      // (16, 65536) f32

    const size_t need_bf16 = (size_t)NB * GPB2 * DIM * 2;   // 64 MB
    const size_t need_f32  = (size_t)NB * GPB2 * DIM * 4;   // 128 MB

    if (ws_size >= need_bf16) {
        uint32_t* part = (uint32_t*)d_ws;
        f1_gen_reduce_bf16<<<NB * GPB2, TPB, 0, stream>>>(x, res4, part);
        f2_final_bf16<<<(NB * DIM / 4) / 256, 256, 0, stream>>>(
            (const u32x2*)part, (const f32x4*)bias4, (f32x4*)y);
    } else if (ws_size >= need_f32) {
        float* part = (float*)d_ws;
        f1_gen_reduce_512<<<NB * GPB2, TPB, 0, stream>>>(x, res4, part);
        f2_final_32<<<(NB * DIM / 4) / 256, 256, 0, stream>>>(
            (const f32x4*)part, (const f32x4*)bias4, (f32x4*)y);
    } else {
        init_bias_kernel<<<(NB * DIM / 4) / 256, 256, 0, stream>>>(bias4, (float4*)y);
        hyper_scatter<<<(NB * NK) / 256, 256, 0, stream>>>(x, res4, y);
    }
}

// Round 13
// 161.352 us; speedup vs baseline: 1.2892x; 1.0131x over previous
//
#include <hip/hip_runtime.h>
#include <stdint.h>
#include <math.h>

// Problem constants (from reference)
#define NB 16
#define NK 16384
#define NADD 32
#define NP 36            // 2^RANK + ADD = 4 + 32
#define DIM 65536        // IN_DIM == OUT_DIM

// geometry: 512 blocks x 512 threads, 64 KB LDS, 2 blocks/CU (128 KB/CU)
#define TPB 512
#define GPB2 32          // groups per batch row (NK / TPB)
#define NCH3 4           // output chunks per batch row
#define CHW3 16384       // chunk width (floats) -> 64 KB LDS accumulator

typedef float f32x4 __attribute__((ext_vector_type(4)));
typedef unsigned int u32x2 __attribute__((ext_vector_type(2)));

__device__ __forceinline__ uint32_t rotl32(uint32_t x, uint32_t r) {
    return (x << r) | (x >> (32u - r));
}

// Threefry-2x32 (20 rounds), key = (0, 42); partitionable mode: ctr=(0,idx),
// bits = out0 ^ out1. CONFIRMED bit-correct (rounds 1-12).
__device__ __forceinline__ uint32_t tf_bits(uint32_t idx) {
    const uint32_t K1 = 42u;
    const uint32_t K2 = 0x1BD11BDAu ^ 42u;
    uint32_t x0 = 0u;
    uint32_t x1 = idx + K1;
#define TF_ROUND(r) { x0 += x1; x1 = rotl32(x1, r); x1 ^= x0; }
#define TF_G(a,b,c,d) TF_ROUND(a) TF_ROUND(b) TF_ROUND(c) TF_ROUND(d)
    TF_G(13,15,26,6)   x0 += K1;  x1 += K2 + 1u;
    TF_G(17,29,16,24)  x0 += K2;  x1 += 2u;
    TF_G(13,15,26,6)              x1 += K1 + 3u;
    TF_G(17,29,16,24)  x0 += K1;  x1 += K2 + 4u;
    TF_G(13,15,26,6)   x0 += K2;  x1 += 5u;
#undef TF_G
#undef TF_ROUND
    return x0 ^ x1;
}

// Bit-exact XLA:CPU f32 exp (Cephes/Eigen pexp), strict per-op f32 rounding,
// no FMA contraction. CONFIRMED: rounds 3-12 passed.
__device__ __forceinline__ float xla_expf(float x0) {
    float x = fminf(fmaxf(x0, -88.3762626647949f), 88.3762626647950f);
    const float fx = floorf(__fadd_rn(__fmul_rn(x, 1.44269504088896341f), 0.5f));
    const float tmp = __fmul_rn(fx, 0.693359375f);
    float z = __fmul_rn(fx, -2.12194440e-4f);
    float r = __fsub_rn(x, tmp);
    r = __fsub_rn(r, z);
    z = __fmul_rn(r, r);
    float y = 1.9875691500E-4f;
    y = __fadd_rn(__fmul_rn(y, r), 1.3981999507E-3f);
    y = __fadd_rn(__fmul_rn(y, r), 8.3334519073E-3f);
    y = __fadd_rn(__fmul_rn(y, r), 4.1665795894E-2f);
    y = __fadd_rn(__fmul_rn(y, r), 1.6666665459E-1f);
    y = __fadd_rn(__fmul_rn(y, r), 5.0000001201E-1f);
    y = __fadd_rn(__fmul_rn(y, z), r);
    y = __fadd_rn(y, 1.0f);
    const int n = (int)fx;
    const float p2n = __uint_as_float((uint32_t)(n + 127) << 23);
    return fmaxf(__fmul_rn(y, p2n), x0);
}

// Shared generation: fills packed[36] ((out<<16)|in) and w[36] (normalized
// weight scale*prop). Identical arithmetic to all passing rounds (3-12).
__device__ __forceinline__ void gen_point(const float4 r, uint32_t tid,
                                          uint32_t* packed, float* w) {
    const float e0 = xla_expf(-r.x);
    const float e1 = xla_expf(-r.y);
    const float s0 = __fdiv_rn(1.0f, __fadd_rn(1.0f, e0));
    const float s1 = __fdiv_rn(1.0f, __fadd_rn(1.0f, e1));
    const float m0 = __fmul_rn(s0, 65535.0f);
    const float m1 = __fmul_rn(s1, 65535.0f);

    const float a2 = r.z + 2.0f;
    const float sp = fmaxf(a2, 0.0f) + log1pf(expf(-fabsf(a2)));
    const float sigma = (sp + 1e-6f) * 65536.0f;
    const float val = r.w;

    const float f0 = floorf(m0), c0 = ceilf(m0);
    const float f1 = floorf(m1), c1 = ceilf(m1);
    {
        const float cd0[4] = {f0, f0, c0, c0};
        const float cd1[4] = {f1, c1, f1, c1};
        #pragma unroll
        for (int p = 0; p < 4; ++p) {
            const float z0 = (cd0[p] - m0) / sigma;
            const float z1 = (cd1[p] - m1) / sigma;
            w[p] = expf(-0.5f * (z0*z0 + z1*z1));
            packed[p] = ((uint32_t)(int)cd0[p] << 16) | (uint32_t)(int)cd1[p];
        }
    }
    const float ONE_MEPS = (float)(1.0 - 1e-6);
    const uint32_t base = tid * 64u;
    #pragma unroll
    for (int a = 0; a < NADD; ++a) {
        const uint32_t bb0 = tf_bits(base + 2u*(uint32_t)a);
        const uint32_t bb1 = tf_bits(base + 2u*(uint32_t)a + 1u);
        const float u0 = __fmul_rn(__uint_as_float((bb0 >> 9) | 0x3f800000u) - 1.0f, ONE_MEPS);
        const float u1 = __fmul_rn(__uint_as_float((bb1 >> 9) | 0x3f800000u) - 1.0f, ONE_MEPS);
        const float s0f = floorf(__fmul_rn(u0, 65536.0f));
        const float s1f = floorf(__fmul_rn(u1, 65536.0f));
        const float z0 = (s0f - m0) / sigma;
        const float z1 = (s1f - m1) / sigma;
        w[4 + a] = expf(-0.5f * (z0*z0 + z1*z1));
        packed[4 + a] = ((uint32_t)(int)s0f << 16) | (uint32_t)(int)s1f;
    }
    float denom = 0.0f;
    #pragma unroll
    for (int p = 0; p < NP; ++p) denom += w[p] + 1e-6f;
    const float scale = val / denom;
    #pragma unroll
    for (int p = 0; p < NP; ++p) w[p] *= scale;
}

// bf16 RNE pack of two f32 into one u32 (a -> low 16, b -> high 16)
__device__ __forceinline__ uint32_t bf16pair(float a, float b) {
    uint32_t ua = __float_as_uint(a), ub = __float_as_uint(b);
    ua = (ua + 0x7FFFu + ((ua >> 16) & 1u)) >> 16;
    ub = (ub + 0x7FFFu + ((ub >> 16) & 1u)) >> 16;
    return ua | (ub << 16);
}

// ------- primary: 512x512, 64 KB LDS (4 passes), bf16 partials (64 MB) ----
// Round-13 change: 4 chunks instead of 8 -> scatter scan drops 288->144
// wave-level predicated ds_add issues per thread, barriers 17->9.
// Partial layout: row = DIM bf16 = 32768 u32 -> row offset = blk << 15 (u32);
// chunk c = 16384 bf16 = 8192 u32 = 4096 u32x2.

__global__ __launch_bounds__(TPB, 4) void f1_gen_reduce_bf16(
    const float*  __restrict__ x,     // (NB, DIM)
    const float4* __restrict__ res4,  // (NB, NK, 4)
    uint32_t* __restrict__ part)      // [NB*GPB2][DIM] bf16
{
    __shared__ float acc[CHW3];       // 64 KB -> 2 blocks/CU (128 KB)
    f32x4* const acc4 = reinterpret_cast<f32x4*>(acc);
    const int blk = blockIdx.x;
    const uint32_t tid = (uint32_t)blk * TPB + threadIdx.x;  // global point id
    const int b = (int)(tid >> 14);

    uint32_t packed[NP];
    float    w[NP];
    gen_point(res4[tid], tid, packed, w);

    const float* __restrict__ xrow = x + ((size_t)b << 16);
    #pragma unroll
    for (int p = 0; p < NP; ++p) {
        w[p] *= xrow[packed[p] & 0xFFFFu];
        packed[p] = packed[p] >> 16;            // out in [0, 65536)
    }

    // initial zero: 4096 f32x4 / 512 threads = 8 iters
    #pragma unroll
    for (int j = 0; j < 8; ++j)
        acc4[j * TPB + threadIdx.x] = (f32x4)(0.0f);
    __syncthreads();

    uint32_t* __restrict__ dst = part + ((size_t)blk << 15);  // u32 row
    #pragma unroll 1
    for (uint32_t c = 0; c < NCH3; ++c) {
        #pragma unroll
        for (int p = 0; p < NP; ++p) {
            if ((packed[p] >> 14) == c)
                atomicAdd(&acc[packed[p] & (CHW3 - 1)], w[p]);
        }
        __syncthreads();
        // merged drain: pack bf16, nontemporal store, re-zero in one sweep.
        // chunk = 4096 u32x2; 4096/512 = 8 iters
        u32x2* __restrict__ dst2 =
            reinterpret_cast<u32x2*>(dst + (size_t)c * 8192);
        #pragma unroll
        for (int j = 0; j < 8; ++j) {
            const int idx = j * TPB + (int)threadIdx.x;   // [0, 4096) u32x2
            const f32x4 v = acc4[idx];
            const u32x2 o = { bf16pair(v.x, v.y), bf16pair(v.z, v.w) };
            __builtin_nontemporal_store(o, &dst2[idx]);
            acc4[idx] = (f32x4)(0.0f);                    // re-zero for next pass
        }
        __syncthreads();
    }
}

// F2: y = bias + sum_g bf16 part rows; fully coalesced, nontemporal.
__global__ __launch_bounds__(256) void f2_final_bf16(
    const u32x2* __restrict__ part2,  // [NB*GPB2][16384] u32x2
    const f32x4* __restrict__ bias4,
    f32x4* __restrict__ y4)
{
    const int i = blockIdx.x * 256 + threadIdx.x;  // [0, NB*DIM/4)
    const int o4 = i & 16383;                      // u32x2 index within row
    const int b = i >> 14;
    f32x4 s = bias4[o4];
    #pragma unroll
    for (int g = 0; g < GPB2; ++g) {
        const u32x2 p = __builtin_nontemporal_load(
            &part2[(((size_t)(b * GPB2 + g)) << 14) + o4]);
        s.x += __uint_as_float(p.x << 16);
        s.y += __uint_as_float(p.x & 0xFFFF0000u);
        s.z += __uint_as_float(p.y << 16);
        s.w += __uint_as_float(p.y & 0xFFFF0000u);
    }
    __builtin_nontemporal_store(s, &y4[i]);
}

// ---------------- fallback path (round-3 passing kernel) ----------------

__global__ __launch_bounds__(256) void init_bias_kernel(
    const float4* __restrict__ bias4, float4* __restrict__ y4)
{
    const int i = blockIdx.x * 256 + threadIdx.x;
    y4[i] = bias4[i & 16383];
}

__global__ __launch_bounds__(256) void hyper_scatter(
    const float*  __restrict__ x,
    const float4* __restrict__ res4,
    float*        __restrict__ y)
{
    const int tid = blockIdx.x * 256 + threadIdx.x;
    const int b = tid >> 14;
    uint32_t packed[NP];
    float    w[NP];
    gen_point(res4[tid], (uint32_t)tid, packed, w);
    const float* __restrict__ xrow = x + ((size_t)b << 16);
    float*       __restrict__ yrow = y + ((size_t)b << 16);
    #pragma unroll
    for (int p = 0; p < NP; ++p) {
        const float xv = xrow[packed[p] & 0xFFFFu];
        unsafeAtomicAdd(&yrow[packed[p] >> 16], w[p] * xv);
    }
}

extern "C" void kernel_launch(void* const* d_in, const int* in_sizes, int n_in,
                              void* d_out, int out_size, void* d_ws, size_t ws_size,
                              hipStream_t stream) {
    const float*  x     = (const float*)d_in[0];   // (16, 65536) f32
    const float4* res4  = (const float4*)d_in[1];  // (16, 16384, 4) f32
    const float4* bias4 = (const float4*)d_in[2];  // (65536,) f32
    float* y = (float*)d_out;                      // (16, 65536) f32

    const size_t need_bf16 = (size_t)NB * GPB2 * DIM * 2;   // 64 MB

    if (ws_size >= need_bf16) {
        uint32_t* part = (uint32_t*)d_ws;
        f1_gen_reduce_bf16<<<NB * GPB2, TPB, 0, stream>>>(x, res4, part);
        f2_final_bf16<<<(NB * DIM / 4) / 256, 256, 0, stream>>>(
            (const u32x2*)part, (const f32x4*)bias4, (f32x4*)y);
    } else {
        init_bias_kernel<<<(NB * DIM / 4) / 256, 256, 0, stream>>>(bias4, (float4*)y);
        hyper_scatter<<<(NB * NK) / 256, 256, 0, stream>>>(x, res4, y);
    }
}